// Round 10
// baseline (452.634 us; speedup 1.0000x reference)
//
#include <hip/hip_runtime.h>
#include <math.h>

#define NPFS   4
#define NFM    512
#define NP     256
#define BATCH  128
#define NBLK   (BATCH * NPFS)   // 512 pfaffians
#define THREADS 512
#define NWAVES (THREADS / 64)   // 8
#define TRI    ((NP * (NP - 1)) / 2)   // 32640 strict-lower elements
#define NB     4                 // steps per panel block -> rank-8 trailing update
#define BSTEPS (2 * NB)          // 8 columns consumed per block

typedef _Float16 half_t;
typedef _Float16 h4 __attribute__((ext_vector_type(4)));

// fp16 packed strict-lower triangle, each row padded to a multiple of 4
// elements so every row starts 8B-aligned (h4 loads). rowoff(256) = 33024.
__device__ __forceinline__ int rowoff(int r) {
    int q = r >> 2, rem = r & 3;
    int g = 2 * q * q + q;
    if (rem > 0) g += q;
    if (rem > 1) g += q + 1;
    if (rem > 2) g += q + 1;
    return g << 2;
}

// rank-8 update chain — EXACT jj-ascending order (same form as all passing kernels)
__device__ __forceinline__ float4 rank8_upd(float4 l, float4 t4, float4 v4,
    const float4 tj0, const float4 tj1, const float4 tj2, const float4 tj3,
    const float4 vj0, const float4 vj1, const float4 vj2, const float4 vj3)
{
    l.x += v4.x * tj0.x - t4.x * vj0.x;
    l.y += v4.x * tj0.y - t4.x * vj0.y;
    l.z += v4.x * tj0.z - t4.x * vj0.z;
    l.w += v4.x * tj0.w - t4.x * vj0.w;
    l.x += v4.y * tj1.x - t4.y * vj1.x;
    l.y += v4.y * tj1.y - t4.y * vj1.y;
    l.z += v4.y * tj1.z - t4.y * vj1.z;
    l.w += v4.y * tj1.w - t4.y * vj1.w;
    l.x += v4.z * tj2.x - t4.z * vj2.x;
    l.y += v4.z * tj2.y - t4.z * vj2.y;
    l.z += v4.z * tj2.z - t4.z * vj2.z;
    l.w += v4.z * tj2.w - t4.z * vj2.w;
    l.x += v4.w * tj3.x - t4.w * vj3.x;
    l.y += v4.w * tj3.y - t4.w * vj3.y;
    l.z += v4.w * tj3.z - t4.w * vj3.z;
    l.w += v4.w * tj3.w - t4.w * vj3.w;
    return l;
}

extern "C" __global__ __launch_bounds__(THREADS, 4)
void MultiPf_32469952758284_kernel(const float* __restrict__ F,
                                   const int* __restrict__ idx,
                                   float* __restrict__ ws)
{
    extern __shared__ char smemc[];
    half_t* Lh    = (half_t*)smemc;                 // 33024 h (66048 B)
    float* Tcol   = (float*)(smemc + 66048);        // NB*256 f (tau_j, col-major)
    float* Vcol   = (float*)(smemc + 70144);        // NB*256 f (v_j, col-major)
    float* colbuf = (float*)(smemc + 74240);        // 256 f (fp32 pivot column seed)
    int*   idxL   = (int*)(smemc + 75264);          // 256
    // total 76288 B; 512-thread blocks -> TWO blocks/CU co-resident.
    // The two blocks' latency-bound single-wave panels interleave on the CU.
    // launch_bounds(512,4): VGPR cap 128 -> no scratch spill (round-8 lesson).

    const int tid = threadIdx.x;
    const int bid = blockIdx.x;
    const int b = bid >> 2;   // batch
    const int s = bid & 3;    // pf-state
    const float* __restrict__ Fs = F + (size_t)s * NFM * NFM;

    if (tid < NP) idxL[tid] = idx[b * NP + tid];
    __syncthreads();

    // ---- gather strict lower triangle: A[r][c] = 0.5*(F[ir][ic] - F[ic][ir])
    // L stored fp16; colbuf (pivot-search seed column) kept fp32.
    for (int e = tid; e < TRI; e += THREADS) {
        int r = (int)((1.0f + sqrtf(1.0f + 8.0f * (float)e)) * 0.5f);
        while (r * (r - 1) / 2 > e) --r;
        while (r * (r + 1) / 2 <= e) ++r;
        int c = e - r * (r - 1) / 2;
        int ir = idxL[r], ic = idxL[c];
        float val = 0.5f * (Fs[(size_t)ir * NFM + ic] - Fs[(size_t)ic * NFM + ir]);
        Lh[rowoff(r) + c] = (half_t)val;
        if (c == 0) colbuf[r] = val;
    }

    float sgn = 1.0f, la = 0.0f;   // maintained on wave 0; tid 0 writes out
    __syncthreads();

    for (int kb = 0; kb < NP / BSTEPS; ++kb) {
        const int k0 = kb * BSTEPS;

        // ========== panel: NB steps, single wave, ZERO barriers ==========
        // (round-3-proven structure; fp16 L + fp32 colbuf seed from round 9;
        //  ascending-jj FMA chains identical to round 9 -> bit-identical.)
        if (tid < 64) {
            const int lane = tid;
            #pragma unroll
            for (int j = 0; j < NB; ++j) {
                const int k = k0 + 2 * j;
                const int p = k + 1;

                // fence: prev step's P2/A2 LDS writes (cross-lane) visible
                asm volatile("s_waitcnt lgkmcnt(0)" ::: "memory");
                __builtin_amdgcn_sched_barrier(0);

                // uniform panel values at row k (k >= k_jj+2 for jj<j -> live)
                float tk0 = 0.f, vk0 = 0.f, tk1 = 0.f, vk1 = 0.f, tk2 = 0.f, vk2 = 0.f;
                if (j > 0) { tk0 = Tcol[0 * NP + k]; vk0 = Vcol[0 * NP + k]; }
                if (j > 1) { tk1 = Tcol[1 * NP + k]; vk1 = Vcol[1 * NP + k]; }
                if (j > 2) { tk2 = Tcol[2 * NP + k]; vk2 = Vcol[2 * NP + k]; }

                // A1: refresh pivot column k into registers.
                // j==0: trailing-seeded fp32 colbuf (unrounded, = round 9).
                float x[4];
                #pragma unroll
                for (int ii = 0; ii < 4; ++ii) {
                    const int r = lane + 64 * ii;
                    x[ii] = 0.0f;
                    if (r > k) {
                        float xv;
                        if (j == 0) {
                            xv = colbuf[r];
                        } else {
                            xv = (float)Lh[rowoff(r) + k];
                            xv += Vcol[0 * NP + r] * tk0 - Tcol[0 * NP + r] * vk0;
                            if (j > 1) xv += Vcol[1 * NP + r] * tk1 - Tcol[1 * NP + r] * vk1;
                            if (j > 2) xv += Vcol[2 * NP + r] * tk2 - Tcol[2 * NP + r] * vk2;
                        }
                        x[ii] = xv;
                    }
                }

                // argmax_{r>k} |x[r]|, tie -> lowest r (matches jnp.argmax).
                // key = (|x|<<32) | ((255-r)<<1) | signbit; winner's float bits
                // reconstructed from the key (round-3-proven, absmax 0 there).
                unsigned long long key = 0ull;
                #pragma unroll
                for (int ii = 0; ii < 4; ++ii) {
                    const int r = lane + 64 * ii;
                    if (r > k) {
                        const unsigned int bits = __float_as_uint(x[ii]);
                        const unsigned int ab = bits & 0x7fffffffu;
                        const unsigned long long kk =
                            ((unsigned long long)ab << 32) |
                            ((unsigned)(NP - 1 - r) << 1) | (bits >> 31);
                        if (kk > key) key = kk;
                    }
                }
                #pragma unroll
                for (int o = 1; o < 64; o <<= 1) {
                    const unsigned long long ok = __shfl_xor(key, o);
                    if (ok > key) key = ok;
                }
                const int kp = (NP - 1) - (int)((key >> 1) & 0xffu);
                const unsigned int csb =
                    (unsigned int)(key >> 32) | ((unsigned int)(key & 1u) << 31);
                const float cs = __uint_as_float(csb);
                const float piv = -cs;          // piv = A_post[k][k+1] = -L_pre[kp][k]
                const float rpiv = 1.0f / piv;
                if (kp != p) sgn = -sgn;
                if (piv < 0.0f) sgn = -sgn;
                la += logf(fabsf(piv));

                // refreshed col-k value at row p -> row kp's tau after swap
                const int slot = p >> 6, sl = p & 63;
                const float xsel = (slot == 0) ? x[0] : (slot == 1) ? x[1]
                                  : (slot == 2) ? x[2] : x[3];
                const float xp = __shfl(xsel, sl);

                // uniform pre-swap panel values at row kp (= post-swap row p)
                float tp0 = 0.f, vp0 = 0.f, tp1 = 0.f, vp1 = 0.f, tp2 = 0.f, vp2 = 0.f;
                if (j > 0) { tp0 = Tcol[0 * NP + kp]; vp0 = Vcol[0 * NP + kp]; }
                if (j > 1) { tp1 = Tcol[1 * NP + kp]; vp1 = Vcol[1 * NP + kp]; }
                if (j > 2) { tp2 = Tcol[2 * NP + kp]; vp2 = Vcol[2 * NP + kp]; }

                // P2: symmetric swap (p<->kp) on Lh; capture post-swap column p.
                // Each (row,element) touched by exactly one lane -> race-free.
                // Col-k swap dropped (col k is dead; tau comes from x / xp).
                float vsw[4];
                #pragma unroll
                for (int ii = 0; ii < 4; ++ii) vsw[ii] = 0.0f;
                if (kp == p) {
                    #pragma unroll
                    for (int ii = 0; ii < 4; ++ii) {
                        const int r = lane + 64 * ii;
                        if (r >= k + 2) vsw[ii] = (float)Lh[rowoff(r) + p];
                    }
                } else {
                    const int okp = rowoff(kp);
                    #pragma unroll
                    for (int ii = 0; ii < 4; ++ii) {
                        const int r = lane + 64 * ii;
                        if (r >= k + 2) {
                            const int orr = rowoff(r);
                            if (r < kp) {
                                const float a0 = (float)Lh[orr + p];
                                const float a1 = (float)Lh[okp + r];
                                Lh[orr + p] = (half_t)(-a1);
                                Lh[okp + r] = (half_t)(-a0);
                                vsw[ii] = -a1;
                            } else if (r == kp) {
                                const float wv = -(float)Lh[orr + p];
                                Lh[orr + p] = (half_t)wv; vsw[ii] = wv;
                            } else { // r > kp
                                const half_t t = Lh[orr + p], u2 = Lh[orr + kp];
                                Lh[orr + p] = u2; Lh[orr + kp] = t;
                                vsw[ii] = (float)u2;
                            }
                        }
                    }
                    // physical swap of rows p,kp in accumulated panels (jj<j)
                    if (lane < j) {
                        const int jj = lane;
                        float a, b2;
                        a = Tcol[jj * NP + p]; b2 = Tcol[jj * NP + kp];
                        Tcol[jj * NP + p] = b2; Tcol[jj * NP + kp] = a;
                        a = Vcol[jj * NP + p]; b2 = Vcol[jj * NP + kp];
                        Vcol[jj * NP + p] = b2; Vcol[jj * NP + kp] = a;
                    }
                }
                asm volatile("s_waitcnt lgkmcnt(0)" ::: "memory");
                __builtin_amdgcn_sched_barrier(0);

                // A2: refresh column p (post-swap) + extract tau/v into slot j.
                // Row values read post-swap from LDS; uniforms tp*/vp* are the
                // post-swap row-p values (pre-swap row kp). Ascending jj chain.
                #pragma unroll
                for (int ii = 0; ii < 4; ++ii) {
                    const int r = lane + 64 * ii;
                    if (r >= k + 2) {
                        const float tau = ((r == kp) ? xp : x[ii]) * rpiv;
                        float y = vsw[ii];
                        if (j > 0) y += Vcol[0 * NP + r] * tp0 - Tcol[0 * NP + r] * vp0;
                        if (j > 1) y += Vcol[1 * NP + r] * tp1 - Tcol[1 * NP + r] * vp1;
                        if (j > 2) y += Vcol[2 * NP + r] * tp2 - Tcol[2 * NP + r] * vp2;
                        Tcol[j * NP + r] = tau;
                        Vcol[j * NP + r] = y;
                    }
                }
            }
        }
        __syncthreads();   // panel results visible to all waves

        // ================= trailing rank-2*NB update (round-9 verbatim) =====
        const int kend = k0 + BSTEPS;   // multiple of 8 -> h4 aligned
        if (kend < NP) {
            const int w = tid >> 6;
            const int lane = tid & 63;
            if (NP - kend > 128) {
                // ---- 1 row per wave-iteration (front half: many columns)
                const int c0 = kend + (lane << 2);
                float4 tj0 = {0,0,0,0}, tj1 = {0,0,0,0}, tj2 = {0,0,0,0}, tj3 = {0,0,0,0};
                float4 vj0 = {0,0,0,0}, vj1 = {0,0,0,0}, vj2 = {0,0,0,0}, vj3 = {0,0,0,0};
                if (c0 < NP) {
                    tj0 = *(const float4*)(Tcol + 0 * NP + c0);
                    tj1 = *(const float4*)(Tcol + 1 * NP + c0);
                    tj2 = *(const float4*)(Tcol + 2 * NP + c0);
                    tj3 = *(const float4*)(Tcol + 3 * NP + c0);
                    vj0 = *(const float4*)(Vcol + 0 * NP + c0);
                    vj1 = *(const float4*)(Vcol + 1 * NP + c0);
                    vj2 = *(const float4*)(Vcol + 2 * NP + c0);
                    vj3 = *(const float4*)(Vcol + 3 * NP + c0);
                }
                for (int r = kend + 1 + w; r < NP; r += NWAVES) {
                    if (c0 < r) {
                        const float4 t4 = {Tcol[0 * NP + r], Tcol[1 * NP + r],
                                           Tcol[2 * NP + r], Tcol[3 * NP + r]};
                        const float4 v4 = {Vcol[0 * NP + r], Vcol[1 * NP + r],
                                           Vcol[2 * NP + r], Vcol[3 * NP + r]};
                        h4* Lp = (h4*)(Lh + rowoff(r) + c0);
                        const h4 lh = *Lp;
                        float4 l = {(float)lh.x, (float)lh.y, (float)lh.z, (float)lh.w};
                        l = rank8_upd(l, t4, v4, tj0, tj1, tj2, tj3,
                                      vj0, vj1, vj2, vj3);
                        h4 oh;
                        oh.x = (half_t)l.x; oh.y = (half_t)l.y;
                        oh.z = (half_t)l.z; oh.w = (half_t)l.w;
                        *Lp = oh;
                        if (lane == 0) colbuf[r] = l.x;   // column kend (fp32)
                    }
                }
            } else {
                // ---- 2 rows per wave-iteration (back half: <=128 columns):
                // lanes 0-31 -> row r, lanes 32-63 -> row r+1.
                const int sub = lane & 31, hlf = lane >> 5;
                const int c0 = kend + (sub << 2);
                float4 tj0 = {0,0,0,0}, tj1 = {0,0,0,0}, tj2 = {0,0,0,0}, tj3 = {0,0,0,0};
                float4 vj0 = {0,0,0,0}, vj1 = {0,0,0,0}, vj2 = {0,0,0,0}, vj3 = {0,0,0,0};
                if (c0 < NP) {
                    tj0 = *(const float4*)(Tcol + 0 * NP + c0);
                    tj1 = *(const float4*)(Tcol + 1 * NP + c0);
                    tj2 = *(const float4*)(Tcol + 2 * NP + c0);
                    tj3 = *(const float4*)(Tcol + 3 * NP + c0);
                    vj0 = *(const float4*)(Vcol + 0 * NP + c0);
                    vj1 = *(const float4*)(Vcol + 1 * NP + c0);
                    vj2 = *(const float4*)(Vcol + 2 * NP + c0);
                    vj3 = *(const float4*)(Vcol + 3 * NP + c0);
                }
                for (int rr = kend + 1 + 2 * w; rr < NP; rr += 2 * NWAVES) {
                    const int r = rr + hlf;
                    if (r < NP && c0 < r) {
                        const float4 t4 = {Tcol[0 * NP + r], Tcol[1 * NP + r],
                                           Tcol[2 * NP + r], Tcol[3 * NP + r]};
                        const float4 v4 = {Vcol[0 * NP + r], Vcol[1 * NP + r],
                                           Vcol[2 * NP + r], Vcol[3 * NP + r]};
                        h4* Lp = (h4*)(Lh + rowoff(r) + c0);
                        const h4 lh = *Lp;
                        float4 l = {(float)lh.x, (float)lh.y, (float)lh.z, (float)lh.w};
                        l = rank8_upd(l, t4, v4, tj0, tj1, tj2, tj3,
                                      vj0, vj1, vj2, vj3);
                        h4 oh;
                        oh.x = (half_t)l.x; oh.y = (half_t)l.y;
                        oh.z = (half_t)l.z; oh.w = (half_t)l.w;
                        *Lp = oh;
                        if (sub == 0) colbuf[r] = l.x;   // column kend (fp32)
                    }
                }
            }
        }
        __syncthreads();   // trailing + colbuf visible to next panel
    }

    if (tid == 0) {
        ws[bid * 2 + 0] = sgn;
        ws[bid * 2 + 1] = la;
    }
}

extern "C" __global__ void MultiPf_combine_kernel(const float* __restrict__ ws,
                                                  float* __restrict__ out)
{
    int b = threadIdx.x + blockIdx.x * blockDim.x;
    if (b >= BATCH) return;
    float sg[NPFS], lg[NPFS];
    float m = -INFINITY;
    for (int j = 0; j < NPFS; ++j) {
        sg[j] = ws[(b * NPFS + j) * 2 + 0];
        lg[j] = ws[(b * NPFS + j) * 2 + 1];
        m = fmaxf(m, lg[j]);
    }
    float val = 0.0f;
    for (int j = 0; j < NPFS; ++j)
        val += sg[j] * expf(lg[j] - m);
    float osgn = (val > 0.0f) ? 1.0f : ((val < 0.0f) ? -1.0f : 0.0f);
    out[b]         = osgn;
    out[BATCH + b] = m + logf(fabsf(val));
}

extern "C" void kernel_launch(void* const* d_in, const int* in_sizes, int n_in,
                              void* d_out, int out_size, void* d_ws, size_t ws_size,
                              hipStream_t stream)
{
    (void)in_sizes; (void)n_in; (void)out_size; (void)ws_size;
    const float* F   = (const float*)d_in[0];
    const int*   idx = (const int*)d_in[1];
    float* out = (float*)d_out;
    float* ws  = (float*)d_ws;

    const size_t smem_bytes = 76288;   // see LDS layout in kernel (2 blocks/CU)

    // Raise dynamic-LDS cap above the 64 KB default (gfx950: 160 KB/CU).
    (void)hipFuncSetAttribute((const void*)MultiPf_32469952758284_kernel,
                              hipFuncAttributeMaxDynamicSharedMemorySize,
                              (int)smem_bytes);

    MultiPf_32469952758284_kernel<<<NBLK, THREADS, smem_bytes, stream>>>(F, idx, ws);
    MultiPf_combine_kernel<<<1, 128, 0, stream>>>(ws, out);
}